// Round 3
// baseline (280.966 us; speedup 1.0000x reference)
//
#include <hip/hip_runtime.h>
#include <stdint.h>

#define NTOK 8192   // B*T
#define D 1024
#define E 8
#define BM 256
#define BN 256
#define BK 64
#define NKT (D / BK)          // 16 K-iters
#define BUFE (BM * BK)        // 16384 elements per A/B buffer

typedef __attribute__((ext_vector_type(8))) short short8;
typedef __attribute__((ext_vector_type(4))) float f32x4;

// fp32 -> bf16 bits, round-to-nearest-even
__device__ __forceinline__ ushort f2bf(float f) {
  uint32_t x = __float_as_uint(f);
  x += 0x7FFFu + ((x >> 16) & 1u);
  return (ushort)(x >> 16);
}

// One fused dispatch: convert expert_W -> bf16, convert delta -> bf16,
// zero out (32 MB), zero cnt.
#define NW4 2097152   // E*D*D/4
#define ND4 2097152   // NTOK*D/4
#define NO4 2097152   // NTOK*D/4 (out, float4)
__global__ __launch_bounds__(256) void convert_zero_kernel(
    const float* __restrict__ expert_W, const float* __restrict__ delta,
    ushort* __restrict__ Wb, ushort* __restrict__ Db,
    float* __restrict__ out, int* __restrict__ cnt) {
  int i = blockIdx.x * 256 + threadIdx.x;
  if (i < E) cnt[i] = 0;
  if (i < NW4) {
    float4 v = ((const float4*)expert_W)[i];
    ushort4 u; u.x = f2bf(v.x); u.y = f2bf(v.y); u.z = f2bf(v.z); u.w = f2bf(v.w);
    ((ushort4*)Wb)[i] = u;
  } else if (i < NW4 + ND4) {
    int j = i - NW4;
    float4 v = ((const float4*)delta)[j];
    ushort4 u; u.x = f2bf(v.x); u.y = f2bf(v.y); u.z = f2bf(v.z); u.w = f2bf(v.w);
    ((ushort4*)Db)[j] = u;
  } else {
    int j = i - NW4 - ND4;
    ((float4*)out)[j] = (float4){0.f, 0.f, 0.f, 0.f};
  }
}

// Wave per token: fp32 logits, top-2, softmax. No global atomics.
__global__ __launch_bounds__(256) void gate_topk_kernel(
    const float* __restrict__ x, const float* __restrict__ gW,
    const float* __restrict__ gb,
    int* __restrict__ idx01, float2* __restrict__ w01) {
  int wave = threadIdx.x >> 6;
  int lane = threadIdx.x & 63;
  int t = blockIdx.x * 4 + wave;

  const float4* xr = (const float4*)(x + (size_t)t * D) + lane * 4;
  float acc[E];
#pragma unroll
  for (int e = 0; e < E; ++e) acc[e] = 0.f;
#pragma unroll
  for (int q = 0; q < 4; ++q) {
    float4 xv = xr[q];
#pragma unroll
    for (int e = 0; e < E; ++e) {
      float4 wv = ((const float4*)(gW + e * D))[lane * 4 + q];
      acc[e] += xv.x * wv.x + xv.y * wv.y + xv.z * wv.z + xv.w * wv.w;
    }
  }
#pragma unroll
  for (int e = 0; e < E; ++e) {
    float v = acc[e];
#pragma unroll
    for (int off = 32; off > 0; off >>= 1) v += __shfl_xor(v, off, 64);
    acc[e] = v;
  }
  if (lane == 0) {
    float lg[E];
#pragma unroll
    for (int e = 0; e < E; ++e) lg[e] = acc[e] + gb[e];
    int i0 = 0; float v0 = lg[0];
#pragma unroll
    for (int e = 1; e < E; ++e) { if (lg[e] > v0) { v0 = lg[e]; i0 = e; } }
    int i1 = -1; float v1 = -1e30f;
#pragma unroll
    for (int e = 0; e < E; ++e) { if (e != i0 && lg[e] > v1) { v1 = lg[e]; i1 = e; } }
    float e1 = __expf(v1 - v0);
    float inv = 1.f / (1.f + e1);
    idx01[t] = i0 | (i1 << 16);
    w01[t] = make_float2(inv, e1 * inv);
  }
}

// Counting-sort into per-expert lists. LDS histogram, 8 global atomics/block.
__global__ __launch_bounds__(256) void bin_kernel(
    const int* __restrict__ idx01, const float2* __restrict__ w01,
    int* __restrict__ cnt, int* __restrict__ list, float* __restrict__ wlist) {
  __shared__ int hist[E];
  __shared__ int base[E];
  int tid = threadIdx.x;
  int t = blockIdx.x * 256 + tid;
  if (tid < E) hist[tid] = 0;
  __syncthreads();

  int packed = idx01[t];
  float2 w = w01[t];
  int i0 = packed & 0xFFFF, i1 = packed >> 16;
  int r0 = atomicAdd(&hist[i0], 1);
  int r1 = atomicAdd(&hist[i1], 1);
  __syncthreads();
  if (tid < E) base[tid] = atomicAdd(&cnt[tid], hist[tid]);
  __syncthreads();

  int s0 = base[i0] + r0;
  list[i0 * NTOK + s0] = t; wlist[i0 * NTOK + s0] = w.x;
  int s1 = base[i1] + r1;
  list[i1 * NTOK + s1] = t; wlist[i1 * NTOK + s1] = w.y;
}

// Grouped GEMM v4: 2-phase double-buffered pipeline (T3 minimum recipe),
// BM=BN=256, BK=64, 8 waves (512 thr). Per wave: 128x64 output (acc 8x4),
// per K-iter 24 ds_read_b128 vs 64 MFMA (MFMA-bound compute phase).
// Loop: STAGE(tile k+1 -> buf^1) issued FIRST, then compute buf, then ONE
// __syncthreads (its vmcnt(0) drain waits on loads issued a full compute
// phase earlier -> latency hidden in-block; no cross-block TLP needed).
// Anchor: m248v2 grouped K=1024 2ph 256^2 = 655 TF.
// LDS 128 KB (2 dbuf x (A 32K + B 32K)), 1 block/CU.
// XOR swizzle unchanged: slot(row,s) holds granule s^(row&7), granule=16B.
__global__ __launch_bounds__(512) void moe_gemm_kernel(
    const ushort* __restrict__ Db, const ushort* __restrict__ Wb,
    const float* __restrict__ eb, const int* __restrict__ cnt,
    const int* __restrict__ list, const float* __restrict__ wlist,
    float* __restrict__ out) {
  // bx = mt*32 + e*4 + nt ; same-(e,nt) blocks share bx%8 -> same XCD L2
  int bx = blockIdx.x;
  int mt = bx >> 5;
  int rem = bx & 31;
  int e = rem >> 2;
  int nt = rem & 3;
  int M = cnt[e];
  int m0 = mt * BM;
  if (m0 >= M) return;
  int n0 = nt * BN;

  __shared__ ushort As[2 * BM * BK];  // 64 KB
  __shared__ ushort Bs[2 * BN * BK];  // 64 KB

  int tid = threadIdx.x;
  int wave = tid >> 6;   // 0..7
  int lane = tid & 63;
  int wm = wave >> 2;    // 0..1 : 128-row halves
  int wn = wave & 3;     // 0..3 : 64-col quarters
  const int c = lane & 15;
  const int q = lane >> 4;

  const int* listE = list + e * NTOK;

  // Staging: each wave covers 32 rows via 4 insts of 8 rows x 8 granules.
  // lane l -> row +(l>>3), LDS slot l&7, global granule (l&7)^(l>>3)
  // (row&7 == l>>3 since all subtile base rows are %8==0).
  int rloc = lane >> 3;                 // 0..7
  int gglob = (lane & 7) ^ rloc;        // swizzled source granule
  const ushort* aptr[4];
  ushort* alds[4];
#pragma unroll
  for (int p = 0; p < 4; ++p) {
    int r = m0 + wave * 32 + p * 8 + rloc;
    int tok = listE[r < M ? r : m0];    // clamp padded rows (real token data)
    aptr[p] = Db + (size_t)tok * D + gglob * 8;
    alds[p] = &As[(wave * 32 + p * 8) * BK];
  }
  const ushort* WbE = Wb + ((size_t)e << 20);
  const ushort* bptr[4];
  ushort* blds[4];
#pragma unroll
  for (int p = 0; p < 4; ++p) {
    int row = n0 + wave * 32 + p * 8 + rloc;
    bptr[p] = WbE + (size_t)row * D + gglob * 8;
    blds[p] = &Bs[(wave * 32 + p * 8) * BK];
  }

  f32x4 acc[8][4];
#pragma unroll
  for (int i = 0; i < 8; ++i)
#pragma unroll
    for (int j = 0; j < 4; ++j)
      acc[i][j] = (f32x4){0.f, 0.f, 0.f, 0.f};

  // Prologue: stage tile 0 into buf 0
#pragma unroll
  for (int p = 0; p < 4; ++p) {
    __builtin_amdgcn_global_load_lds(
        (const __attribute__((address_space(1))) void*)(aptr[p]),
        (__attribute__((address_space(3))) void*)(alds[p]), 16, 0, 0);
    __builtin_amdgcn_global_load_lds(
        (const __attribute__((address_space(1))) void*)(bptr[p]),
        (__attribute__((address_space(3))) void*)(blds[p]), 16, 0, 0);
  }
  __syncthreads();

  for (int kt = 0; kt < NKT; ++kt) {
    int cur = (kt & 1) * BUFE;
    // Issue next-tile loads FIRST (into the other buffer).
    if (kt < NKT - 1) {
      int nxt = ((kt + 1) & 1) * BUFE;
      int kk = (kt + 1) * BK;
#pragma unroll
      for (int p = 0; p < 4; ++p) {
        __builtin_amdgcn_global_load_lds(
            (const __attribute__((address_space(1))) void*)(aptr[p] + kk),
            (__attribute__((address_space(3))) void*)(alds[p] + nxt), 16, 0, 0);
        __builtin_amdgcn_global_load_lds(
            (const __attribute__((address_space(1))) void*)(bptr[p] + kk),
            (__attribute__((address_space(3))) void*)(blds[p] + nxt), 16, 0, 0);
      }
    }
    const ushort* Ab = As + cur;
    const ushort* Bb = Bs + cur;
#pragma unroll
    for (int s = 0; s < 2; ++s) {
      // granule g = s*4+q; swizzled LDS slot = g ^ (row&7), row&7 = c&7
      int sw = (((s * 4 + q) ^ (c & 7)) * 8);
      short8 a[8], b[4];
#pragma unroll
      for (int i = 0; i < 8; ++i)
        a[i] = *(const short8*)&Ab[(wm * 128 + i * 16 + c) * BK + sw];
#pragma unroll
      for (int j = 0; j < 4; ++j)
        b[j] = *(const short8*)&Bb[(wn * 64 + j * 16 + c) * BK + sw];
#pragma unroll
      for (int i = 0; i < 8; ++i)
#pragma unroll
        for (int j = 0; j < 4; ++j)
          acc[i][j] = __builtin_amdgcn_mfma_f32_16x16x32_bf16(a[i], b[j], acc[i][j], 0, 0, 0);
    }
    // One barrier per iter: drains this iter's prefetch (hidden under MFMA)
    // and makes buf[cur] safe to overwrite next iter.
    __syncthreads();
  }

  // Epilogue: C/D layout col=lane&15, row=(lane>>4)*4+reg
  float bias[4];
#pragma unroll
  for (int j = 0; j < 4; ++j)
    bias[j] = eb[e * D + n0 + wn * 64 + j * 16 + c];
  const float* wlE = wlist + e * NTOK;
#pragma unroll
  for (int i = 0; i < 8; ++i) {
#pragma unroll
    for (int r = 0; r < 4; ++r) {
      int m = m0 + wm * 128 + i * 16 + q * 4 + r;
      if (m < M) {
        int tok = listE[m];
        float w = wlE[m];
        float* orow = out + (size_t)tok * D + n0 + wn * 64 + c;
#pragma unroll
        for (int j = 0; j < 4; ++j)
          atomicAdd(&orow[j * 16], (acc[i][j][r] + bias[j]) * w);
      }
    }
  }
}

extern "C" void kernel_launch(void* const* d_in, const int* in_sizes, int n_in,
                              void* d_out, int out_size, void* d_ws, size_t ws_size,
                              hipStream_t stream) {
  const float* input_feat = (const float*)d_in[0];
  const float* delta      = (const float*)d_in[1];
  const float* gate_W     = (const float*)d_in[2];
  const float* gate_b     = (const float*)d_in[3];
  const float* expert_W   = (const float*)d_in[4];
  const float* expert_b   = (const float*)d_in[5];
  float* out = (float*)d_out;

  // ws: Wb 16MiB | Db 16MiB | cnt | list | wlist | idx01 | w01
  char* ws = (char*)d_ws;
  ushort* Wb    = (ushort*)ws;
  ushort* Db    = (ushort*)(ws + 16777216);
  char*   meta  = ws + 2 * 16777216;
  int*    cnt   = (int*)meta;
  int*    list  = (int*)(meta + 256);
  float*  wlist = (float*)(meta + 256 + NTOK * E * 4);
  int*    idx01 = (int*)(meta + 256 + 2 * NTOK * E * 4);
  float2* w01   = (float2*)(meta + 256 + 2 * NTOK * E * 4 + NTOK * 4);

  int total4 = NW4 + ND4 + NO4;
  convert_zero_kernel<<<total4 / 256, 256, 0, stream>>>(expert_W, delta, Wb, Db, out, cnt);
  gate_topk_kernel<<<NTOK / 4, 256, 0, stream>>>(input_feat, gate_W, gate_b, idx01, w01);
  bin_kernel<<<NTOK / 256, 256, 0, stream>>>(idx01, w01, cnt, list, wlist);
  // grid: 32 mt x 8 e x 4 nt = 1024 blocks (~288 working, 1/CU by LDS)
  moe_gemm_kernel<<<(NTOK / BM) * E * (D / BN), 512, 0, stream>>>(
      Db, Wb, expert_b, cnt, list, wlist, out);
}

// Round 4
// 229.759 us; speedup vs baseline: 1.2229x; 1.2229x over previous
//
#include <hip/hip_runtime.h>
#include <hip/hip_fp16.h>
#include <stdint.h>

#define NTOK 8192   // B*T
#define D 1024
#define E 8
#define BM 128
#define BN 64
#define BK 64

typedef __attribute__((ext_vector_type(8))) short short8;
typedef __attribute__((ext_vector_type(4))) float f32x4;

// fp32 -> bf16 bits, round-to-nearest-even
__device__ __forceinline__ ushort f2bf(float f) {
  uint32_t x = __float_as_uint(f);
  x += 0x7FFFu + ((x >> 16) & 1u);
  return (ushort)(x >> 16);
}

__device__ __forceinline__ ushort f2h(float f) {
  union { __half h; ushort u; } c;
  c.h = __float2half(f);
  return c.u;
}
__device__ __forceinline__ float h2f(ushort u) {
  union { __half h; ushort u; } c;
  c.u = u;
  return __half2float(c.h);
}

// Convert expert_W -> bf16, delta -> bf16, zero cnt. (out-zero REMOVED:
// packed-halves epilogue writes every byte of out exactly once.)
#define NW4 2097152   // E*D*D/4
#define ND4 2097152   // NTOK*D/4
__global__ __launch_bounds__(256) void convert_kernel(
    const float* __restrict__ expert_W, const float* __restrict__ delta,
    ushort* __restrict__ Wb, ushort* __restrict__ Db, int* __restrict__ cnt) {
  int i = blockIdx.x * 256 + threadIdx.x;
  if (i < E) cnt[i] = 0;
  if (i < NW4) {
    float4 v = ((const float4*)expert_W)[i];
    ushort4 u; u.x = f2bf(v.x); u.y = f2bf(v.y); u.z = f2bf(v.z); u.w = f2bf(v.w);
    ((ushort4*)Wb)[i] = u;
  } else {
    int j = i - NW4;
    float4 v = ((const float4*)delta)[j];
    ushort4 u; u.x = f2bf(v.x); u.y = f2bf(v.y); u.z = f2bf(v.z); u.w = f2bf(v.w);
    ((ushort4*)Db)[j] = u;
  }
}

// Fused gate + bin: wave per token (4 tokens/block); top-2 + softmax; then
// block-level counting-append into per-expert lists (8 global atomics/block).
// List entry encodes rank in bit 31 (rank0 -> low f16 half of out word,
// rank1 -> high half).
__global__ __launch_bounds__(256) void gatebin_kernel(
    const float* __restrict__ x, const float* __restrict__ gW,
    const float* __restrict__ gb, int* __restrict__ cnt,
    int* __restrict__ list, float* __restrict__ wlist) {
  int wave = threadIdx.x >> 6;
  int lane = threadIdx.x & 63;
  int tid = threadIdx.x;
  int t = blockIdx.x * 4 + wave;

  const float4* xr = (const float4*)(x + (size_t)t * D) + lane * 4;
  float acc[E];
#pragma unroll
  for (int e = 0; e < E; ++e) acc[e] = 0.f;
#pragma unroll
  for (int q = 0; q < 4; ++q) {
    float4 xv = xr[q];
#pragma unroll
    for (int e = 0; e < E; ++e) {
      float4 wv = ((const float4*)(gW + e * D))[lane * 4 + q];
      acc[e] += xv.x * wv.x + xv.y * wv.y + xv.z * wv.z + xv.w * wv.w;
    }
  }
#pragma unroll
  for (int e = 0; e < E; ++e) {
    float v = acc[e];
#pragma unroll
    for (int off = 32; off > 0; off >>= 1) v += __shfl_xor(v, off, 64);
    acc[e] = v;
  }

  __shared__ int sIdx[4];      // packed i0 | i1<<16 per wave
  __shared__ float2 sW[4];
  __shared__ int hist[E];
  __shared__ int base[E];
  __shared__ int rofs[4][2];   // within-block rank offsets

  if (lane == 0) {
    float lg[E];
#pragma unroll
    for (int e = 0; e < E; ++e) lg[e] = acc[e] + gb[e];
    int i0 = 0; float v0 = lg[0];
#pragma unroll
    for (int e = 1; e < E; ++e) { if (lg[e] > v0) { v0 = lg[e]; i0 = e; } }
    int i1 = -1; float v1 = -1e30f;
#pragma unroll
    for (int e = 0; e < E; ++e) { if (e != i0 && lg[e] > v1) { v1 = lg[e]; i1 = e; } }
    float e1 = __expf(v1 - v0);
    float inv = 1.f / (1.f + e1);
    sIdx[wave] = i0 | (i1 << 16);
    sW[wave] = make_float2(inv, e1 * inv);
  }
  if (tid < E) hist[tid] = 0;
  __syncthreads();

  if (tid == 0) {
#pragma unroll
    for (int w4 = 0; w4 < 4; ++w4) {
      int p = sIdx[w4];
      rofs[w4][0] = hist[p & 0xFFFF]++;
      rofs[w4][1] = hist[p >> 16]++;
    }
  }
  __syncthreads();
  if (tid < E) base[tid] = hist[tid] ? atomicAdd(&cnt[tid], hist[tid]) : 0;
  __syncthreads();

  if (tid == 0) {
#pragma unroll
    for (int w4 = 0; w4 < 4; ++w4) {
      int p = sIdx[w4];
      int tk = blockIdx.x * 4 + w4;
      int e0 = p & 0xFFFF, e1 = p >> 16;
      int s0 = base[e0] + rofs[w4][0];
      list[e0 * NTOK + s0] = tk;                         // rank 0
      wlist[e0 * NTOK + s0] = sW[w4].x;
      int s1 = base[e1] + rofs[w4][1];
      list[e1 * NTOK + s1] = tk | 0x80000000;            // rank 1
      wlist[e1 * NTOK + s1] = sW[w4].y;
    }
  }
}

// Grouped GEMM (R0-proven structure: BM=128,BN=64,BK=64, 1-phase, 24KB LDS,
// 6-8 blocks/CU TLP hides the per-iter VMEM latency). ONLY the epilogue
// changed: instead of 32 fp32 atomicAdds/thread, store each contribution as
// f16 into its rank's 2-byte half of the f32 out word (disjoint bytes, no
// races, no zero-init needed). combine_kernel sums the halves afterwards.
// LDS layout: slot (row, s) holds global granule s ^ (row&7) (granule=16B).
__global__ __launch_bounds__(256) void moe_gemm_kernel(
    const ushort* __restrict__ Db, const ushort* __restrict__ Wb,
    const float* __restrict__ eb, const int* __restrict__ cnt,
    const int* __restrict__ list, const float* __restrict__ wlist,
    float* __restrict__ out) {
  // bx = mt*128 + e*16 + nt  (mt slow: first 2048 blocks all alive)
  int bx = blockIdx.x;
  int mt = bx >> 7;
  int rem = bx & 127;
  int e = rem >> 4;
  int nt = rem & 15;
  int M = cnt[e];
  int m0 = mt * BM;
  if (m0 >= M) return;
  int n0 = nt * BN;

  __shared__ ushort As[BM * BK];  // 16 KB
  __shared__ ushort Bs[BN * BK];  // 8 KB

  int tid = threadIdx.x;
  int wave = tid >> 6;
  int lane = tid & 63;
  int wm = wave >> 1;   // 0..1 : 64 rows
  int wn = wave & 1;    // 0..1 : 32 cols
  const int c = lane & 15;
  const int q = lane >> 4;

  const int* listE = list + e * NTOK;

  // Staging: inst covers 8 rows x 8 granules; lane l -> row +(l>>3), slot l&7,
  // fetches global granule (l&7)^(l>>3)  (row&7 == l>>3 since bases are %8==0).
  int rloc = lane >> 3;                 // 0..7
  int gglob = (lane & 7) ^ rloc;        // swizzled source granule
  const ushort* aptr[4];
  ushort* alds[4];
#pragma unroll
  for (int p = 0; p < 4; ++p) {
    int r = m0 + wave * 32 + p * 8 + rloc;
    int tok = listE[r < M ? r : m0] & 0x7FFFFFFF;   // clamp padded rows
    aptr[p] = Db + (size_t)tok * D + gglob * 8;
    alds[p] = &As[(wave * 32 + p * 8) * BK];
  }
  const ushort* WbE = Wb + ((size_t)e << 20);
  const ushort* bptr[2];
  ushort* blds[2];
#pragma unroll
  for (int sub = 0; sub < 2; ++sub) {
    int row = n0 + wave * 16 + sub * 8 + rloc;
    bptr[sub] = WbE + (size_t)row * D + gglob * 8;
    blds[sub] = &Bs[(wave * 16 + sub * 8) * BK];
  }

  f32x4 acc[4][2];
#pragma unroll
  for (int i = 0; i < 4; ++i)
#pragma unroll
    for (int j = 0; j < 2; ++j)
      acc[i][j] = (f32x4){0.f, 0.f, 0.f, 0.f};

  for (int k0 = 0; k0 < D; k0 += BK) {
#pragma unroll
    for (int p = 0; p < 4; ++p)
      __builtin_amdgcn_global_load_lds(
          (const __attribute__((address_space(1))) void*)(aptr[p] + k0),
          (__attribute__((address_space(3))) void*)alds[p], 16, 0, 0);
#pragma unroll
    for (int sub = 0; sub < 2; ++sub)
      __builtin_amdgcn_global_load_lds(
          (const __attribute__((address_space(1))) void*)(bptr[sub] + k0),
          (__attribute__((address_space(3))) void*)blds[sub], 16, 0, 0);
    __syncthreads();

#pragma unroll
    for (int s = 0; s < 2; ++s) {
      // granule g = s*4+q; swizzled LDS slot = g ^ (row&7), row&7 = c&7
      int sw = (((s * 4 + q) ^ (c & 7)) * 8);
      short8 a[4], b[2];
#pragma unroll
      for (int i = 0; i < 4; ++i)
        a[i] = *(const short8*)&As[(wm * 64 + i * 16 + c) * BK + sw];
#pragma unroll
      for (int j = 0; j < 2; ++j)
        b[j] = *(const short8*)&Bs[(wn * 32 + j * 16 + c) * BK + sw];
#pragma unroll
      for (int i = 0; i < 4; ++i)
#pragma unroll
        for (int j = 0; j < 2; ++j)
          acc[i][j] = __builtin_amdgcn_mfma_f32_16x16x32_bf16(a[i], b[j], acc[i][j], 0, 0, 0);
    }
    __syncthreads();
  }

  // Epilogue: C/D layout col=lane&15, row=(lane>>4)*4+reg.
  // Store f16 contribution into rank's half of out word. No atomics.
  float bias[2];
#pragma unroll
  for (int j = 0; j < 2; ++j)
    bias[j] = eb[e * D + n0 + wn * 32 + j * 16 + c];
  const float* wlE = wlist + e * NTOK;
  ushort* outh = (ushort*)out;
#pragma unroll
  for (int i = 0; i < 4; ++i) {
#pragma unroll
    for (int r = 0; r < 4; ++r) {
      int m = m0 + wm * 64 + i * 16 + q * 4 + r;
      if (m < M) {
        int en = listE[m];
        int tok = en & 0x7FFFFFFF;
        int rank = ((unsigned)en) >> 31;
        float w = wlE[m];
        size_t bi = ((size_t)tok * D + n0 + wn * 32 + c) * 2 + rank;
#pragma unroll
        for (int j = 0; j < 2; ++j)
          outh[bi + j * 32] = f2h((acc[i][j][r] + bias[j]) * w);
      }
    }
  }
}

// Sum the two packed f16 halves of each out word -> f32, in place.
#define NC4 2097152   // NTOK*D/4
__global__ __launch_bounds__(256) void combine_kernel(float* __restrict__ out) {
  int i = blockIdx.x * 256 + threadIdx.x;
  uint4 v = ((const uint4*)out)[i];
  float4 r;
  r.x = h2f((ushort)(v.x & 0xFFFF)) + h2f((ushort)(v.x >> 16));
  r.y = h2f((ushort)(v.y & 0xFFFF)) + h2f((ushort)(v.y >> 16));
  r.z = h2f((ushort)(v.z & 0xFFFF)) + h2f((ushort)(v.z >> 16));
  r.w = h2f((ushort)(v.w & 0xFFFF)) + h2f((ushort)(v.w >> 16));
  ((float4*)out)[i] = r;
}

extern "C" void kernel_launch(void* const* d_in, const int* in_sizes, int n_in,
                              void* d_out, int out_size, void* d_ws, size_t ws_size,
                              hipStream_t stream) {
  const float* input_feat = (const float*)d_in[0];
  const float* delta      = (const float*)d_in[1];
  const float* gate_W     = (const float*)d_in[2];
  const float* gate_b     = (const float*)d_in[3];
  const float* expert_W   = (const float*)d_in[4];
  const float* expert_b   = (const float*)d_in[5];
  float* out = (float*)d_out;

  // ws: Wb 16MiB | Db 16MiB | cnt | list | wlist   (~33.05 MB total)
  char* ws = (char*)d_ws;
  ushort* Wb    = (ushort*)ws;
  ushort* Db    = (ushort*)(ws + 16777216);
  char*   meta  = ws + 2 * 16777216;
  int*    cnt   = (int*)meta;
  int*    list  = (int*)(meta + 256);
  float*  wlist = (float*)(meta + 256 + NTOK * E * 4);

  convert_kernel<<<(NW4 + ND4) / 256, 256, 0, stream>>>(expert_W, delta, Wb, Db, cnt);
  gatebin_kernel<<<NTOK / 4, 256, 0, stream>>>(input_feat, gate_W, gate_b, cnt, list, wlist);
  moe_gemm_kernel<<<(NTOK / BM) * 128, 256, 0, stream>>>(
      Db, Wb, expert_b, cnt, list, wlist, out);
  combine_kernel<<<NC4 / 256, 256, 0, stream>>>(out);
}